// Round 14
// baseline (116.287 us; speedup 1.0000x reference)
//
#include <hip/hip_runtime.h>

#define S_LEN 2048
#define D_DIM 128
#define NBH   32
#define LOG2E 1.44269504f
#define NEGM  -1000000.0f

typedef __bf16 bf16x8 __attribute__((ext_vector_type(8)));
typedef short  s16x8  __attribute__((ext_vector_type(8)));
typedef float  f32x4  __attribute__((ext_vector_type(4)));
typedef float  f32x16 __attribute__((ext_vector_type(16)));
typedef unsigned int u32x4 __attribute__((ext_vector_type(4)));

static __device__ __forceinline__ unsigned short f32_to_bf16_bits_exact(float f) {
    return (unsigned short)(__float_as_uint(f) >> 16);   // exact for small ints
}
static __device__ __forceinline__ float round_away(float t) {
    float r = floorf(fabsf(t) + 0.5f);
    return (t >= 0.0f) ? r : -r;
}
// p0,p1 -> one u32 of two bf16(floor(fma(p,127,0.5))) via v_perm
static __device__ __forceinline__ unsigned int pq_pack(float p0, float p1) {
    float a = floorf(fmaf(p0, 127.0f, 0.5f));
    float b = floorf(fmaf(p1, 127.0f, 0.5f));
    return __builtin_amdgcn_perm(__float_as_uint(b), __float_as_uint(a), 0x07060302);
}

// ------- fused: per-token quant of Q,K (blocks 0..16383) + V amax (16384..) -
__global__ __launch_bounds__(256) void quant_qkv_kernel(
    const float* __restrict__ q, const float* __restrict__ k,
    const float* __restrict__ v,
    unsigned short* __restrict__ qq, unsigned short* __restrict__ kq,
    float* __restrict__ qs, float* __restrict__ ks,
    unsigned int* __restrict__ vab)
{
    if (blockIdx.x < 16384) {
        const int R = NBH * S_LEN;
        int w   = blockIdx.x * 8 + (threadIdx.x >> 5);
        int l32 = threadIdx.x & 31;
        const float* src; unsigned short* dq; float* ds; int row;
        if (w < R) { src = q; dq = qq; ds = qs; row = w; }
        else       { src = k; dq = kq; ds = ks; row = w - R; }
        size_t base = (size_t)row * D_DIM + l32 * 4;
        float4 x = *(const float4*)(src + base);
        float amax = fmaxf(fmaxf(fabsf(x.x), fabsf(x.y)), fmaxf(fabsf(x.z), fabsf(x.w)));
        #pragma unroll
        for (int m = 1; m < 32; m <<= 1) amax = fmaxf(amax, __shfl_xor(amax, m));
        float scale = fmaxf(amax, 1e-8f) / 127.0f;
        ushort4 o;
        o.x = f32_to_bf16_bits_exact(fminf(fmaxf(round_away(x.x / scale), -127.0f), 127.0f));
        o.y = f32_to_bf16_bits_exact(fminf(fmaxf(round_away(x.y / scale), -127.0f), 127.0f));
        o.z = f32_to_bf16_bits_exact(fminf(fmaxf(round_away(x.z / scale), -127.0f), 127.0f));
        o.w = f32_to_bf16_bits_exact(fminf(fmaxf(round_away(x.w / scale), -127.0f), 127.0f));
        *(ushort4*)(dq + base) = o;
        if (l32 == 0) ds[row] = scale;
    } else {
        int bid2 = blockIdx.x - 16384;
        int bh = bid2 >> 3, blk = bid2 & 7;
        const float4* base = (const float4*)(v + (size_t)bh * S_LEN * D_DIM) + blk * 8192;
        int t = threadIdx.x;
        float am = 0.0f;
        #pragma unroll
        for (int i = 0; i < 32; ++i) {
            float4 x = base[t + i * 256];
            am = fmaxf(am, fmaxf(fmaxf(fabsf(x.x), fabsf(x.y)), fmaxf(fabsf(x.z), fabsf(x.w))));
        }
        #pragma unroll
        for (int m = 1; m < 64; m <<= 1) am = fmaxf(am, __shfl_xor(am, m));
        __shared__ float red[4];
        if ((t & 63) == 0) red[t >> 6] = am;
        __syncthreads();
        if (t == 0) {
            float a = fmaxf(fmaxf(red[0], red[1]), fmaxf(red[2], red[3]));
            atomicMax(&vab[bh], __float_as_uint(a));
        }
    }
}

// ---------------- V quantize + transpose to [B,H,D,S] ----------------------
__global__ __launch_bounds__(256) void vtq_kernel(const float* __restrict__ v,
                                                  const unsigned int* __restrict__ vab,
                                                  unsigned short* __restrict__ vT)
{
    __shared__ unsigned short tileT[128][72];
    int bh = blockIdx.x >> 5, sb = blockIdx.x & 31;
    float scale = fmaxf(__uint_as_float(vab[bh]), 1e-8f) / 127.0f;
    int t = threadIdx.x;
    const float* src = v + ((size_t)bh * S_LEN + sb * 64) * D_DIM;
    #pragma unroll
    for (int it = 0; it < 8; ++it) {
        int c = t + it * 256;
        int rs = c >> 5, c4 = (c & 31) * 4;
        float4 x = *(const float4*)(src + rs * D_DIM + c4);
        float vals[4] = {x.x, x.y, x.z, x.w};
        #pragma unroll
        for (int u = 0; u < 4; ++u) {
            float r = fminf(fmaxf(round_away(vals[u] / scale), -127.0f), 127.0f);
            tileT[c4 + u][rs] = f32_to_bf16_bits_exact(r);
        }
    }
    __syncthreads();
    unsigned short* dst = vT + (size_t)bh * D_DIM * S_LEN + sb * 64;
    #pragma unroll
    for (int it = 0; it < 4; ++it) {
        int c = t + it * 256;
        int d = c >> 3, c8 = (c & 7) * 8;
        *(s16x8*)(dst + (size_t)d * S_LEN + c8) = *(const s16x8*)&tileT[d][c8];
    }
}

// -------- fused int8 flash attention: 8-wave key-split, swapped 32x32 ------
// LDS map (extern, 73728 B):
//   Kb_h  = smem + h*8192          (2 x 8 KB  : K half-tile, 32 rows x 256B, swz)
//   Vb_h  = smem + 16384 + h*8192  (2 x 8 KB  : V^T half [32 rho][256B], swz)
//   ksl   = smem + 32768           (8 KB      : full ks row)
//   ML    = smem + 34816           (2 KB      : per-half {m,l} for merge)
//   Qlds  = smem + 40960           (32 KB     : Q tile [w4][32 rows][256B], swz)
//   Ol    = smem + 0               (epilogue reuse: 2 x [32][132] f32)
// launch_bounds (512,2): reg cap 256 -> room for K/V prefetch registers.
__global__ __launch_bounds__(512, 2) void attn_kernel(
    const unsigned short* __restrict__ qq,
    const unsigned short* __restrict__ kq,
    const unsigned short* __restrict__ vT,
    const float* __restrict__ qs,
    const float* __restrict__ ks,
    const unsigned int* __restrict__ vab,
    const float* __restrict__ smp,
    float* __restrict__ out)
{
    extern __shared__ char smem[];

    const int tid  = threadIdx.x;
    const int lane = tid & 63;
    const int wid  = tid >> 6;       // 0..7
    const int w4   = wid & 3;
    const int half = wid >> 2;       // key-column half
    const int c32  = lane & 31;
    const int hi   = lane >> 5;
    const int t8   = tid & 255;

    char*   KbH  = smem + half * 8192;
    char*   VbH  = smem + 16384 + half * 8192;
    float*  ksl  = (float*)(smem + 32768);
    float2* ML   = (float2*)(smem + 34816);
    char*   Qlds = smem + 40960;
    float*  Ol   = (float*)smem;

    const int bid = blockIdx.x;
    const int qb  = 15 - (bid >> 5);      // pure LPT: longest WGs dispatched first
    const int bh  = bid & 31;

    const float qk_scale = smp[0] * LOG2E;
    const float vscale   = fmaxf(__uint_as_float(vab[bh]), 1e-8f) / 127.0f;
    const float vs_term  = vscale / 127.0f;

    const int   q  = qb * 128 + c32 * 4 + w4;
    const float qf = qs[(size_t)bh * S_LEN + q] * qk_scale;

    const char* kqb = (const char*)(kq + (size_t)bh * S_LEN * D_DIM);
    const char* vtb = (const char*)(vT + (size_t)bh * D_DIM * S_LEN);

    // ---- prologue staging: ks row (8 KB) + Q tile (32 KB, swizzled) ----
    ((f32x4*)ksl)[tid] = ((const f32x4*)(ks + (size_t)bh * S_LEN))[tid];
    {
        const char* qqb = (const char*)(qq + ((size_t)bh * S_LEN + qb * 128) * D_DIM);
        #pragma unroll
        for (int it = 0; it < 4; ++it) {
            int L = (tid + it * 512) * 16;        // [0, 32768)
            int w = L >> 13, Lw = L & 8191;
            int r = Lw >> 8, x = Lw & 255;
            int col = x ^ ((r & 15) << 4);
            *(s16x8*)(Qlds + L) = *(const s16x8*)(qqb + (r * 4 + w) * 256 + col);
        }
    }

    // per-thread staging offsets (constant over j): linear LDS, pre-swz global
    int kOff[2], vOff[2], lOff[2];
    #pragma unroll
    for (int it = 0; it < 2; ++it) {
        int L = (t8 + it * 256) * 16;             // [0, 8192)
        lOff[it] = L;
        int r = L >> 8, x = L & 255;
        int c = x ^ ((r & 15) << 4);
        kOff[it] = (half * 32 + r) * 256 + c;
        vOff[it] = ((c >> 6) * 32 + r) * (S_LEN * 2) + half * 64 + (c & 63);
    }

    float mrow = -100.0f;            // finite sentinel; real scores are O(1)
    float lrow = 0.0f;
    f32x16 oacc0, oacc1, oacc2, oacc3;
    #pragma unroll
    for (int i = 0; i < 16; ++i) { oacc0[i] = 0.f; oacc1[i] = 0.f; oacc2[i] = 0.f; oacc3[i] = 0.f; }

    const int swz = (c32 & 15) << 4;
    const char* aBase = KbH + c32 * 256;
    const char* bBase = Qlds + w4 * 8192 + c32 * 256;
    const char* vBase = VbH + c32 * 256;

    const int jn = 2 * qb + 2;

    // T14 prefetch registers: tile j+1 issued under tile j's compute
    s16x8 kpre0, kpre1, vpre0, vpre1;
    {
        kpre0 = *(const s16x8*)(kqb + kOff[0]);
        kpre1 = *(const s16x8*)(kqb + kOff[1]);
        vpre0 = *(const s16x8*)(vtb + vOff[0]);
        vpre1 = *(const s16x8*)(vtb + vOff[1]);
    }

    // one full iteration; domask folds at compile time via inlined constant
    auto iter = [&](const int j, const bool domask) __attribute__((always_inline)) {
        __syncthreads();                 // B1: previous tile's readers done
        *(s16x8*)(KbH + lOff[0]) = kpre0;
        *(s16x8*)(KbH + lOff[1]) = kpre1;
        *(s16x8*)(VbH + lOff[0]) = vpre0;
        *(s16x8*)(VbH + lOff[1]) = vpre1;
        if (j + 1 < jn) {                // issue next tile: hides under compute
            const int jb2 = (j + 1) * 64;
            kpre0 = *(const s16x8*)(kqb + jb2 * 256 + kOff[0]);
            kpre1 = *(const s16x8*)(kqb + jb2 * 256 + kOff[1]);
            vpre0 = *(const s16x8*)(vtb + jb2 * 2   + vOff[0]);
            vpre1 = *(const s16x8*)(vtb + jb2 * 2   + vOff[1]);
        }
        __syncthreads();                 // B2: tile ready

        // ---- swapped QK^T: S^T = K_half · Q^T (Q frags from LDS) ----
        f32x16 sc;
        #pragma unroll
        for (int i = 0; i < 16; ++i) sc[i] = 0.f;
        #pragma unroll
        for (int st = 0; st < 8; ++st) {
            int cB = (st * 32 + hi * 16) ^ swz;
            bf16x8 a = __builtin_bit_cast(bf16x8, *(const s16x8*)(aBase + cB));
            bf16x8 b = __builtin_bit_cast(bf16x8, *(const s16x8*)(bBase + cB));
            sc = __builtin_amdgcn_mfma_f32_32x32x16_bf16(a, b, sc, 0, 0, 0);
        }

        // ---- dequant folded with -mrow: t = fma(s_int, qf*kv, -mrow) ----
        const int jb  = j * 64;
        const int jbh = jb + half * 32;
        float mhA = -3.0e38f, mhB = -3.0e38f;
        #pragma unroll
        for (int gg = 0; gg < 4; ++gg) {
            f32x4 kv = *(const f32x4*)&ksl[jbh + gg * 8 + hi * 4];
            #pragma unroll
            for (int i = 0; i < 4; ++i) {
                int r = gg * 4 + i;
                float tv = fmaf(sc[r], qf * kv[i], -mrow);
                if (domask) tv = (q >= jbh + gg * 8 + i + hi * 4) ? tv : NEGM;
                sc[r] = tv;
                if (i & 1) mhB = fmaxf(mhB, tv);
                else       mhA = fmaxf(mhA, tv);
            }
        }
        float mh     = fmaxf(mhA, mhB);
        float vmax_t = fmaxf(mh, __shfl_xor(mh, 32));

        // ---- defer-max (THR=1): rescale only when row max grew by > 1 ----
        if (__any(vmax_t > 1.0f)) {
            float sh    = fmaxf(vmax_t, 0.0f);
            float alpha = exp2f(-sh);
            mrow += sh;
            #pragma unroll
            for (int r = 0; r < 16; ++r) sc[r] -= sh;
            oacc0 *= alpha; oacc1 *= alpha; oacc2 *= alpha; oacc3 *= alpha;
            lrow  *= alpha;
        }

        // ---- p = exp2(t) in place (p <= 2, p_q <= 254: bf16-exact) ----
        float ts[8];
        #pragma unroll
        for (int r = 0; r < 8; ++r) {
            sc[r]     = exp2f(sc[r]);
            sc[r + 8] = exp2f(sc[r + 8]);
            ts[r] = sc[r] + sc[r + 8];
        }
        #pragma unroll
        for (int stp = 4; stp >= 1; stp >>= 1)
            #pragma unroll
            for (int r = 0; r < stp; ++r) ts[r] += ts[r + stp];
        lrow += ts[0] + __shfl_xor(ts[0], 32);

        // ---- pack p_q (bf16), cross-half swap, PV: 8 MFMA ----
        unsigned int W[8];
        #pragma unroll
        for (int gg = 0; gg < 4; ++gg) {
            W[gg*2+0] = pq_pack(sc[gg*4+0], sc[gg*4+1]);
            W[gg*2+1] = pq_pack(sc[gg*4+2], sc[gg*4+3]);
        }
        #pragma unroll
        for (int s = 0; s < 2; ++s) {
            asm("v_permlane32_swap_b32 %0, %1" : "+v"(W[s*4+0]), "+v"(W[s*4+2]));
            asm("v_permlane32_swap_b32 %0, %1" : "+v"(W[s*4+1]), "+v"(W[s*4+3]));
        }
        #pragma unroll
        for (int s = 0; s < 2; ++s) {
            u32x4 uw; uw.x = W[s*4+0]; uw.y = W[s*4+1]; uw.z = W[s*4+2]; uw.w = W[s*4+3];
            bf16x8 bfrag = __builtin_bit_cast(bf16x8, uw);
            int cb = s * 32 + hi * 16;
            bf16x8 va;
            va = __builtin_bit_cast(bf16x8, *(const s16x8*)(vBase + ((cb +   0) ^ swz)));
            oacc0 = __builtin_amdgcn_mfma_f32_32x32x16_bf16(va, bfrag, oacc0, 0, 0, 0);
            va = __builtin_bit_cast(bf16x8, *(const s16x8*)(vBase + ((cb +  64) ^ swz)));
            oacc1 = __builtin_amdgcn_mfma_f32_32x32x16_bf16(va, bfrag, oacc1, 0, 0, 0);
            va = __builtin_bit_cast(bf16x8, *(const s16x8*)(vBase + ((cb + 128) ^ swz)));
            oacc2 = __builtin_amdgcn_mfma_f32_32x32x16_bf16(va, bfrag, oacc2, 0, 0, 0);
            va = __builtin_bit_cast(bf16x8, *(const s16x8*)(vBase + ((cb + 192) ^ swz)));
            oacc3 = __builtin_amdgcn_mfma_f32_32x32x16_bf16(va, bfrag, oacc3, 0, 0, 0);
        }
    };

    // masked lanes exist only for j >= 2*qb (64j+63 > 128qb): peel last 2 iters
    const int jmain = 2 * qb;
    for (int j = 0; j < jmain; ++j) iter(j, false);
    for (int j = jmain; j < jn; ++j) iter(j, true);

    // ---- merge the two key-halves: exchange (m, l) via LDS ----
    __syncthreads();
    if (hi == 0) { float2 ml2; ml2.x = mrow; ml2.y = lrow; ML[half * 128 + w4 * 32 + c32] = ml2; }
    __syncthreads();
    float2 mo  = ML[(1 - half) * 128 + w4 * 32 + c32];
    float  mfin = fmaxf(mrow, mo.x);
    float  bs  = exp2f(mrow - mfin);       // own scale (~0 if this half all-masked)
    float  bo  = exp2f(mo.x - mfin);
    float  lfin = lrow * bs + mo.y * bo;
    const float inv = bs * vs_term / lfin;

    // ---- epilogue: half0 writes scaled O^T, half1 adds, block stores ----
    for (int pass = 0; pass < 2; ++pass) {
        __syncthreads();
        if (half == 0 && (w4 >> 1) == pass) {
            float* reg = Ol + (w4 & 1) * 4224 + c32 * 132;
            #pragma unroll
            for (int r = 0; r < 16; ++r) {
                int drow = (r & 3) + 8 * (r >> 2) + 4 * hi;
                reg[drow]      = oacc0[r] * inv;
                reg[drow + 32] = oacc1[r] * inv;
                reg[drow + 64] = oacc2[r] * inv;
                reg[drow + 96] = oacc3[r] * inv;
            }
        }
        __syncthreads();
        if (half == 1 && (w4 >> 1) == pass) {
            float* reg = Ol + (w4 & 1) * 4224 + c32 * 132;
            #pragma unroll
            for (int r = 0; r < 16; ++r) {
                int drow = (r & 3) + 8 * (r >> 2) + 4 * hi;
                reg[drow]      += oacc0[r] * inv;
                reg[drow + 32] += oacc1[r] * inv;
                reg[drow + 64] += oacc2[r] * inv;
                reg[drow + 96] += oacc3[r] * inv;
            }
        }
        __syncthreads();
        #pragma unroll
        for (int it = 0; it < 4; ++it) {
            int idx = tid + it * 512;
            int w2  = idx >> 10;
            int rem = idx & 1023;
            int row = rem >> 5, c4 = rem & 31;
            f32x4 v4 = *(const f32x4*)(Ol + w2 * 4224 + row * 132 + c4 * 4);
            int qr = qb * 128 + row * 4 + pass * 2 + w2;
            *(f32x4*)(out + ((size_t)bh * S_LEN + qr) * D_DIM + c4 * 4) = v4;
        }
    }
}

extern "C" void kernel_launch(void* const* d_in, const int* in_sizes, int n_in,
                              void* d_out, int out_size, void* d_ws, size_t ws_size,
                              hipStream_t stream)
{
    const float* q  = (const float*)d_in[0];
    const float* k  = (const float*)d_in[1];
    const float* v  = (const float*)d_in[2];
    const float* sm = (const float*)d_in[3];

    if (ws_size < (size_t)50857000) return;
    char* ws = (char*)d_ws;
    unsigned short* qq = (unsigned short*)(ws);
    unsigned short* kq = (unsigned short*)(ws + (1u << 24));
    unsigned short* vT = (unsigned short*)(ws + (2u << 24));
    float*          qs = (float*)(ws + (3u << 24));
    float*          ks = (float*)(ws + (3u << 24) + 262144);
    unsigned int*  vab = (unsigned int*)(ws + (3u << 24) + 524288);
    float*         out = (float*)d_out;

    hipFuncSetAttribute((const void*)attn_kernel,
                        hipFuncAttributeMaxDynamicSharedMemorySize, 73728);

    hipMemsetAsync(vab, 0, NBH * sizeof(unsigned int), stream);
    quant_qkv_kernel<<<dim3(16640), dim3(256), 0, stream>>>(q, k, v, qq, kq, qs, ks, vab);
    vtq_kernel<<<dim3(1024), dim3(256), 0, stream>>>(v, vab, vT);
    attn_kernel<<<dim3(512), dim3(512), 73728, stream>>>(qq, kq, vT, qs, ks, vab, sm, out);
}

// Round 15
// 111.041 us; speedup vs baseline: 1.0472x; 1.0472x over previous
//
#include <hip/hip_runtime.h>

#define S_LEN 2048
#define D_DIM 128
#define NBH   32
#define LOG2E 1.44269504f
#define NEGM  -1000000.0f

typedef __bf16 bf16x8 __attribute__((ext_vector_type(8)));
typedef short  s16x8  __attribute__((ext_vector_type(8)));
typedef float  f32x4  __attribute__((ext_vector_type(4)));
typedef float  f32x16 __attribute__((ext_vector_type(16)));
typedef unsigned int u32x4 __attribute__((ext_vector_type(4)));

static __device__ __forceinline__ unsigned short f32_to_bf16_bits_exact(float f) {
    return (unsigned short)(__float_as_uint(f) >> 16);   // exact for small ints
}
static __device__ __forceinline__ float round_away(float t) {
    float r = floorf(fabsf(t) + 0.5f);
    return (t >= 0.0f) ? r : -r;
}
// p0,p1 -> one u32 of two bf16(floor(fma(p,127,0.5))) via v_perm
static __device__ __forceinline__ unsigned int pq_pack(float p0, float p1) {
    float a = floorf(fmaf(p0, 127.0f, 0.5f));
    float b = floorf(fmaf(p1, 127.0f, 0.5f));
    return __builtin_amdgcn_perm(__float_as_uint(b), __float_as_uint(a), 0x07060302);
}

// ------- fused: per-token quant of Q,K (blocks 0..16383) + V amax (16384..) -
__global__ __launch_bounds__(256) void quant_qkv_kernel(
    const float* __restrict__ q, const float* __restrict__ k,
    const float* __restrict__ v,
    unsigned short* __restrict__ qq, unsigned short* __restrict__ kq,
    float* __restrict__ qs, float* __restrict__ ks,
    unsigned int* __restrict__ vab)
{
    if (blockIdx.x < 16384) {
        const int R = NBH * S_LEN;
        int w   = blockIdx.x * 8 + (threadIdx.x >> 5);
        int l32 = threadIdx.x & 31;
        const float* src; unsigned short* dq; float* ds; int row;
        if (w < R) { src = q; dq = qq; ds = qs; row = w; }
        else       { src = k; dq = kq; ds = ks; row = w - R; }
        size_t base = (size_t)row * D_DIM + l32 * 4;
        float4 x = *(const float4*)(src + base);
        float amax = fmaxf(fmaxf(fabsf(x.x), fabsf(x.y)), fmaxf(fabsf(x.z), fabsf(x.w)));
        #pragma unroll
        for (int m = 1; m < 32; m <<= 1) amax = fmaxf(amax, __shfl_xor(amax, m));
        float scale = fmaxf(amax, 1e-8f) / 127.0f;
        ushort4 o;
        o.x = f32_to_bf16_bits_exact(fminf(fmaxf(round_away(x.x / scale), -127.0f), 127.0f));
        o.y = f32_to_bf16_bits_exact(fminf(fmaxf(round_away(x.y / scale), -127.0f), 127.0f));
        o.z = f32_to_bf16_bits_exact(fminf(fmaxf(round_away(x.z / scale), -127.0f), 127.0f));
        o.w = f32_to_bf16_bits_exact(fminf(fmaxf(round_away(x.w / scale), -127.0f), 127.0f));
        *(ushort4*)(dq + base) = o;
        if (l32 == 0) ds[row] = scale;
    } else {
        int bid2 = blockIdx.x - 16384;
        int bh = bid2 >> 3, blk = bid2 & 7;
        const float4* base = (const float4*)(v + (size_t)bh * S_LEN * D_DIM) + blk * 8192;
        int t = threadIdx.x;
        float am = 0.0f;
        #pragma unroll
        for (int i = 0; i < 32; ++i) {
            float4 x = base[t + i * 256];
            am = fmaxf(am, fmaxf(fmaxf(fabsf(x.x), fabsf(x.y)), fmaxf(fabsf(x.z), fabsf(x.w))));
        }
        #pragma unroll
        for (int m = 1; m < 64; m <<= 1) am = fmaxf(am, __shfl_xor(am, m));
        __shared__ float red[4];
        if ((t & 63) == 0) red[t >> 6] = am;
        __syncthreads();
        if (t == 0) {
            float a = fmaxf(fmaxf(red[0], red[1]), fmaxf(red[2], red[3]));
            atomicMax(&vab[bh], __float_as_uint(a));
        }
    }
}

// ---------------- V quantize + transpose to [B,H,D,S] ----------------------
__global__ __launch_bounds__(256) void vtq_kernel(const float* __restrict__ v,
                                                  const unsigned int* __restrict__ vab,
                                                  unsigned short* __restrict__ vT)
{
    __shared__ unsigned short tileT[128][72];
    int bh = blockIdx.x >> 5, sb = blockIdx.x & 31;
    float scale = fmaxf(__uint_as_float(vab[bh]), 1e-8f) / 127.0f;
    int t = threadIdx.x;
    const float* src = v + ((size_t)bh * S_LEN + sb * 64) * D_DIM;
    #pragma unroll
    for (int it = 0; it < 8; ++it) {
        int c = t + it * 256;
        int rs = c >> 5, c4 = (c & 31) * 4;
        float4 x = *(const float4*)(src + rs * D_DIM + c4);
        float vals[4] = {x.x, x.y, x.z, x.w};
        #pragma unroll
        for (int u = 0; u < 4; ++u) {
            float r = fminf(fmaxf(round_away(vals[u] / scale), -127.0f), 127.0f);
            tileT[c4 + u][rs] = f32_to_bf16_bits_exact(r);
        }
    }
    __syncthreads();
    unsigned short* dst = vT + (size_t)bh * D_DIM * S_LEN + sb * 64;
    #pragma unroll
    for (int it = 0; it < 4; ++it) {
        int c = t + it * 256;
        int d = c >> 3, c8 = (c & 7) * 8;
        *(s16x8*)(dst + (size_t)d * S_LEN + c8) = *(const s16x8*)&tileT[d][c8];
    }
}

// -------- fused int8 flash attention: KVBLK=128, 8-wave key-split ----------
// LDS map (extern, 108544 B):
//   Kb_h  = smem + h*16384          (2 x 16 KB : K half-tile, 64 rows x 256B, swz)
//   Vb_h  = smem + 32768 + h*16384  (2 x 16 KB : V^T half [32 rho][512B], swz)
//   ksl   = smem + 65536            (8 KB      : full ks row)
//   ML    = smem + 73728            (2 KB      : per-half {m,l} for merge)
//   Qlds  = smem + 75776            (32 KB     : Q tile [w4][32 rows][256B], swz)
//   Ol    = smem + 0                (epilogue reuse: 2 x [32][132] f32)
// launch_bounds (512,2): reg cap 256 -> room for 2-tile state + prefetch.
__global__ __launch_bounds__(512, 2) void attn_kernel(
    const unsigned short* __restrict__ qq,
    const unsigned short* __restrict__ kq,
    const unsigned short* __restrict__ vT,
    const float* __restrict__ qs,
    const float* __restrict__ ks,
    const unsigned int* __restrict__ vab,
    const float* __restrict__ smp,
    float* __restrict__ out)
{
    extern __shared__ char smem[];

    const int tid  = threadIdx.x;
    const int lane = tid & 63;
    const int wid  = tid >> 6;       // 0..7
    const int w4   = wid & 3;
    const int half = wid >> 2;       // key-column half
    const int c32  = lane & 31;
    const int hi   = lane >> 5;
    const int t8   = tid & 255;

    char*   KbH  = smem + half * 16384;
    char*   VbH  = smem + 32768 + half * 16384;
    float*  ksl  = (float*)(smem + 65536);
    float2* ML   = (float2*)(smem + 73728);
    char*   Qlds = smem + 75776;
    float*  Ol   = (float*)smem;

    const int bid = blockIdx.x;
    const int qb  = 15 - (bid >> 5);      // pure LPT: longest WGs dispatched first
    const int bh  = bid & 31;

    const float qk_scale = smp[0] * LOG2E;
    const float vscale   = fmaxf(__uint_as_float(vab[bh]), 1e-8f) / 127.0f;
    const float vs_term  = vscale / 127.0f;

    const int   q  = qb * 128 + c32 * 4 + w4;
    const float qf = qs[(size_t)bh * S_LEN + q] * qk_scale;

    const char* kqb = (const char*)(kq + (size_t)bh * S_LEN * D_DIM);
    const char* vtb = (const char*)(vT + (size_t)bh * D_DIM * S_LEN);

    // ---- prologue staging: ks row (8 KB) + Q tile (32 KB, swizzled) ----
    ((f32x4*)ksl)[tid] = ((const f32x4*)(ks + (size_t)bh * S_LEN))[tid];
    {
        const char* qqb = (const char*)(qq + ((size_t)bh * S_LEN + qb * 128) * D_DIM);
        #pragma unroll
        for (int it = 0; it < 4; ++it) {
            int L = (tid + it * 512) * 16;        // [0, 32768)
            int w = L >> 13, Lw = L & 8191;
            int r = Lw >> 8, x = Lw & 255;
            int col = x ^ ((r & 15) << 4);
            *(s16x8*)(Qlds + L) = *(const s16x8*)(qqb + (r * 4 + w) * 256 + col);
        }
    }

    // per-thread staging offsets (constant over d): linear LDS, pre-swz global
    int kOff[4], vOff[4], lOff[4];
    #pragma unroll
    for (int it = 0; it < 4; ++it) {
        int L = (t8 + it * 256) * 16;             // [0, 16384)
        lOff[it] = L;
        int r = L >> 8, x = L & 255;
        int c = x ^ ((r & 15) << 4);
        kOff[it] = (half * 64 + r) * 256 + c;     // key row within 128-key tile
        int rho = L >> 9, xv = L & 511;
        int cv  = xv ^ ((rho & 15) << 4);
        vOff[it] = ((cv >> 7) * 32 + rho) * (S_LEN * 2) + half * 128 + (cv & 127);
    }

    float mrow = -100.0f;            // finite sentinel; real scores are O(1)
    float lrow = 0.0f;
    f32x16 oacc0, oacc1, oacc2, oacc3;
    #pragma unroll
    for (int i = 0; i < 16; ++i) { oacc0[i] = 0.f; oacc1[i] = 0.f; oacc2[i] = 0.f; oacc3[i] = 0.f; }

    const int swz = (c32 & 15) << 4;
    const char* aBase = KbH + c32 * 256;
    const char* bBase = Qlds + w4 * 8192 + c32 * 256;
    const char* vBase = VbH + c32 * 512;

    const int jn_d = qb + 1;                      // 128-key double-tiles

    // prefetch registers: tile d+1 issued under tile d's compute
    s16x8 kpre[4], vpre[4];
    #pragma unroll
    for (int it = 0; it < 4; ++it) {
        kpre[it] = *(const s16x8*)(kqb + kOff[it]);
        vpre[it] = *(const s16x8*)(vtb + vOff[it]);
    }

    // one 128-key iteration; domask folds at compile time
    auto iter = [&](const int d, const bool domask) __attribute__((always_inline)) {
        __syncthreads();                 // B1: previous tile's readers done
        #pragma unroll
        for (int it = 0; it < 4; ++it) *(s16x8*)(KbH + lOff[it]) = kpre[it];
        #pragma unroll
        for (int it = 0; it < 4; ++it) *(s16x8*)(VbH + lOff[it]) = vpre[it];
        if (d + 1 < jn_d) {              // issue next tile: hides under compute
            const int jb2 = (d + 1) * 128;
            #pragma unroll
            for (int it = 0; it < 4; ++it) {
                kpre[it] = *(const s16x8*)(kqb + jb2 * 256 + kOff[it]);
                vpre[it] = *(const s16x8*)(vtb + jb2 * 2   + vOff[it]);
            }
        }
        __syncthreads();                 // B2: tile ready

        // ---- swapped QK^T: two 32-key sub-tiles ----
        f32x16 sc0, sc1;
        #pragma unroll
        for (int i = 0; i < 16; ++i) { sc0[i] = 0.f; sc1[i] = 0.f; }
        #pragma unroll
        for (int st = 0; st < 8; ++st) {
            int cB = (st * 32 + hi * 16) ^ swz;
            bf16x8 a0 = __builtin_bit_cast(bf16x8, *(const s16x8*)(aBase + cB));
            bf16x8 a1 = __builtin_bit_cast(bf16x8, *(const s16x8*)(aBase + 32 * 256 + cB));
            bf16x8 b  = __builtin_bit_cast(bf16x8, *(const s16x8*)(bBase + cB));
            sc0 = __builtin_amdgcn_mfma_f32_32x32x16_bf16(a0, b, sc0, 0, 0, 0);
            sc1 = __builtin_amdgcn_mfma_f32_32x32x16_bf16(a1, b, sc1, 0, 0, 0);
        }

        // ---- dequant folded with -mrow ----
        const int jbh = d * 128 + half * 64;      // this wave's 64-key base
        float mhA = -3.0e38f, mhB = -3.0e38f;
        #pragma unroll
        for (int gg = 0; gg < 4; ++gg) {
            f32x4 kv0 = *(const f32x4*)&ksl[jbh + gg * 8 + hi * 4];
            f32x4 kv1 = *(const f32x4*)&ksl[jbh + 32 + gg * 8 + hi * 4];
            #pragma unroll
            for (int i = 0; i < 4; ++i) {
                int r = gg * 4 + i;
                float tv0 = fmaf(sc0[r], qf * kv0[i], -mrow);
                float tv1 = fmaf(sc1[r], qf * kv1[i], -mrow);
                if (domask) {
                    int key0 = jbh + gg * 8 + i + hi * 4;
                    tv0 = (q >= key0)      ? tv0 : NEGM;
                    tv1 = (q >= key0 + 32) ? tv1 : NEGM;
                }
                sc0[r] = tv0; sc1[r] = tv1;
                if (i & 1) mhB = fmaxf(mhB, fmaxf(tv0, tv1));
                else       mhA = fmaxf(mhA, fmaxf(tv0, tv1));
            }
        }
        float mh     = fmaxf(mhA, mhB);
        float vmax_t = fmaxf(mh, __shfl_xor(mh, 32));

        // ---- defer-max (THR=1): rescale only when row max grew by > 1 ----
        if (__any(vmax_t > 1.0f)) {
            float sh    = fmaxf(vmax_t, 0.0f);
            float alpha = exp2f(-sh);
            mrow += sh;
            #pragma unroll
            for (int r = 0; r < 16; ++r) { sc0[r] -= sh; sc1[r] -= sh; }
            oacc0 *= alpha; oacc1 *= alpha; oacc2 *= alpha; oacc3 *= alpha;
            lrow  *= alpha;
        }

        // ---- p = exp2(t) in place (p <= 2, p_q <= 254: bf16-exact) ----
        float ts[8];
        #pragma unroll
        for (int r = 0; r < 8; ++r) {
            sc0[r]     = exp2f(sc0[r]);
            sc0[r + 8] = exp2f(sc0[r + 8]);
            sc1[r]     = exp2f(sc1[r]);
            sc1[r + 8] = exp2f(sc1[r + 8]);
            ts[r] = (sc0[r] + sc0[r + 8]) + (sc1[r] + sc1[r + 8]);
        }
        #pragma unroll
        for (int stp = 4; stp >= 1; stp >>= 1)
            #pragma unroll
            for (int r = 0; r < stp; ++r) ts[r] += ts[r + stp];
        lrow += ts[0] + __shfl_xor(ts[0], 32);

        // ---- pack p_q (bf16), cross-half swap, PV: 16 MFMA ----
        unsigned int W0[8], W1[8];
        #pragma unroll
        for (int gg = 0; gg < 4; ++gg) {
            W0[gg*2+0] = pq_pack(sc0[gg*4+0], sc0[gg*4+1]);
            W0[gg*2+1] = pq_pack(sc0[gg*4+2], sc0[gg*4+3]);
            W1[gg*2+0] = pq_pack(sc1[gg*4+0], sc1[gg*4+1]);
            W1[gg*2+1] = pq_pack(sc1[gg*4+2], sc1[gg*4+3]);
        }
        #pragma unroll
        for (int s = 0; s < 2; ++s) {
            asm("v_permlane32_swap_b32 %0, %1" : "+v"(W0[s*4+0]), "+v"(W0[s*4+2]));
            asm("v_permlane32_swap_b32 %0, %1" : "+v"(W0[s*4+1]), "+v"(W0[s*4+3]));
            asm("v_permlane32_swap_b32 %0, %1" : "+v"(W1[s*4+0]), "+v"(W1[s*4+2]));
            asm("v_permlane32_swap_b32 %0, %1" : "+v"(W1[s*4+1]), "+v"(W1[s*4+3]));
        }
        #pragma unroll
        for (int t = 0; t < 2; ++t) {
            const unsigned int* Wt = t ? W1 : W0;
            #pragma unroll
            for (int s = 0; s < 2; ++s) {
                u32x4 uw; uw.x = Wt[s*4+0]; uw.y = Wt[s*4+1]; uw.z = Wt[s*4+2]; uw.w = Wt[s*4+3];
                bf16x8 bfrag = __builtin_bit_cast(bf16x8, uw);
                int cb = t * 64 + s * 32 + hi * 16;
                bf16x8 va;
                va = __builtin_bit_cast(bf16x8, *(const s16x8*)(vBase + ((cb +   0) ^ swz)));
                oacc0 = __builtin_amdgcn_mfma_f32_32x32x16_bf16(va, bfrag, oacc0, 0, 0, 0);
                va = __builtin_bit_cast(bf16x8, *(const s16x8*)(vBase + ((cb + 128) ^ swz)));
                oacc1 = __builtin_amdgcn_mfma_f32_32x32x16_bf16(va, bfrag, oacc1, 0, 0, 0);
                va = __builtin_bit_cast(bf16x8, *(const s16x8*)(vBase + ((cb + 256) ^ swz)));
                oacc2 = __builtin_amdgcn_mfma_f32_32x32x16_bf16(va, bfrag, oacc2, 0, 0, 0);
                va = __builtin_bit_cast(bf16x8, *(const s16x8*)(vBase + ((cb + 384) ^ swz)));
                oacc3 = __builtin_amdgcn_mfma_f32_32x32x16_bf16(va, bfrag, oacc3, 0, 0, 0);
            }
        }
    };

    // all masking lives in the final 128-key tile (keys [128qb,128qb+128))
    for (int d = 0; d < jn_d - 1; ++d) iter(d, false);
    iter(jn_d - 1, true);

    // ---- merge the two key-halves: exchange (m, l) via LDS ----
    __syncthreads();
    if (hi == 0) { float2 ml2; ml2.x = mrow; ml2.y = lrow; ML[half * 128 + w4 * 32 + c32] = ml2; }
    __syncthreads();
    float2 mo  = ML[(1 - half) * 128 + w4 * 32 + c32];
    float  mfin = fmaxf(mrow, mo.x);
    float  bs  = exp2f(mrow - mfin);       // own scale (~0 if this half all-masked)
    float  bo  = exp2f(mo.x - mfin);
    float  lfin = lrow * bs + mo.y * bo;
    const float inv = bs * vs_term / lfin;

    // ---- epilogue: half0 writes scaled O^T, half1 adds, block stores ----
    for (int pass = 0; pass < 2; ++pass) {
        __syncthreads();
        if (half == 0 && (w4 >> 1) == pass) {
            float* reg = Ol + (w4 & 1) * 4224 + c32 * 132;
            #pragma unroll
            for (int r = 0; r < 16; ++r) {
                int drow = (r & 3) + 8 * (r >> 2) + 4 * hi;
                reg[drow]      = oacc0[r] * inv;
                reg[drow + 32] = oacc1[r] * inv;
                reg[drow + 64] = oacc2[r] * inv;
                reg[drow + 96] = oacc3[r] * inv;
            }
        }
        __syncthreads();
        if (half == 1 && (w4 >> 1) == pass) {
            float* reg = Ol + (w4 & 1) * 4224 + c32 * 132;
            #pragma unroll
            for (int r = 0; r < 16; ++r) {
                int drow = (r & 3) + 8 * (r >> 2) + 4 * hi;
                reg[drow]      += oacc0[r] * inv;
                reg[drow + 32] += oacc1[r] * inv;
                reg[drow + 64] += oacc2[r] * inv;
                reg[drow + 96] += oacc3[r] * inv;
            }
        }
        __syncthreads();
        #pragma unroll
        for (int it = 0; it < 4; ++it) {
            int idx = tid + it * 512;
            int w2  = idx >> 10;
            int rem = idx & 1023;
            int row = rem >> 5, c4 = rem & 31;
            f32x4 v4 = *(const f32x4*)(Ol + w2 * 4224 + row * 132 + c4 * 4);
            int qr = qb * 128 + row * 4 + pass * 2 + w2;
            *(f32x4*)(out + ((size_t)bh * S_LEN + qr) * D_DIM + c4 * 4) = v4;
        }
    }
}

extern "C" void kernel_launch(void* const* d_in, const int* in_sizes, int n_in,
                              void* d_out, int out_size, void* d_ws, size_t ws_size,
                              hipStream_t stream)
{
    const float* q  = (const float*)d_in[0];
    const float* k  = (const float*)d_in[1];
    const float* v  = (const float*)d_in[2];
    const float* sm = (const float*)d_in[3];

    if (ws_size < (size_t)50857000) return;
    char* ws = (char*)d_ws;
    unsigned short* qq = (unsigned short*)(ws);
    unsigned short* kq = (unsigned short*)(ws + (1u << 24));
    unsigned short* vT = (unsigned short*)(ws + (2u << 24));
    float*          qs = (float*)(ws + (3u << 24));
    float*          ks = (float*)(ws + (3u << 24) + 262144);
    unsigned int*  vab = (unsigned int*)(ws + (3u << 24) + 524288);
    float*         out = (float*)d_out;

    hipFuncSetAttribute((const void*)attn_kernel,
                        hipFuncAttributeMaxDynamicSharedMemorySize, 108544);

    hipMemsetAsync(vab, 0, NBH * sizeof(unsigned int), stream);
    quant_qkv_kernel<<<dim3(16640), dim3(256), 0, stream>>>(q, k, v, qq, kq, qs, ks, vab);
    vtq_kernel<<<dim3(1024), dim3(256), 0, stream>>>(v, vab, vT);
    attn_kernel<<<dim3(512), dim3(512), 108544, stream>>>(qq, kq, vT, qs, ks, vab, sm, out);
}